// Round 12
// baseline (409.066 us; speedup 1.0000x reference)
//
#include <hip/hip_runtime.h>
#include <hip/hip_bf16.h>
#include <math.h>

// Mixer2dTriU: B=64, T=512, C=512, fp32 in/out.
// 6 dispatches (r11 structure, 248 us):
//   prep / ln1_norm_t / gemm_mixer / ln2_norm / gemm_d1 / gemm_d2
//
// GEMM core upgraded r11->r12: 128x128 tile, **BK=128 -> 4 K-iterations**
// (r11's BK=64/8-iter confirmed the per-iteration fixed-cost model; iteration
// count is the lever).  128 KB dbuf is harness-fatal, so: SINGLE 64 KB LDS
// buffer (A[128][128] + B[128][128] bf16) + register prefetch of the next
// tile (8 x uint4/thread).  Loop: issue reg loads -> MFMA (4 k-slices) ->
// sync (LDS reads done, reg loads landed) -> reg->LDS write -> sync.
// acc is only 32 VGPR (vs r6's 128 that spilled); peak live ~110 < 128 cap
// of (512,4).  Spill canary: d1 WRITE_SIZE must stay 32768 KB.
// Swizzle: 16 chunks/row, phys = logical ^ (row&15) -> quarter-wave reads
// cover all 16 slots = free 2-way.  Prologue tile via global_load_lds
// (linear dest, inverse-permuted source).  setprio, bijective XCD swizzle.

#define B_ 64
#define T_ 512
#define C_ 512
#define TC_ (T_ * C_)
static_assert(TC_ == 262144, "");

typedef __attribute__((ext_vector_type(8))) short bf16x8;
typedef __attribute__((ext_vector_type(4))) float f32x4;

__device__ __forceinline__ unsigned short f2bf(float f) {
  union { float f; unsigned u; } v; v.f = f;
  unsigned r = v.u + 0x7FFF + ((v.u >> 16) & 1);   // RNE
  return (unsigned short)(r >> 16);
}
__device__ __forceinline__ float bf2f(unsigned short h) {
  union { unsigned u; float f; } v; v.u = ((unsigned)h) << 16; return v.f;
}

// async global -> LDS, 16 B per lane (global_load_lds_dwordx4)
__device__ __forceinline__ void load16_lds(const void* gsrc, void* ldst) {
  __builtin_amdgcn_global_load_lds(
      (const __attribute__((address_space(1))) unsigned int*)gsrc,
      (__attribute__((address_space(3))) unsigned int*)ldst,
      16, 0, 0);
}

// ------------- prep: weights->bf16 + ln1 partial stats + zero red2 -------------
__global__ __launch_bounds__(256) void prep(
    const float* __restrict__ triM, const float* __restrict__ d1w,
    const float* __restrict__ d2w, unsigned short* __restrict__ Mb,
    unsigned short* __restrict__ W1b, unsigned short* __restrict__ W2b,
    const float* __restrict__ x, float* __restrict__ red1p,
    float* __restrict__ red2) {
  if (blockIdx.x < 1024) {
    if (blockIdx.x == 0 && threadIdx.x < 128) red2[threadIdx.x] = 0.f;
    const int idx = blockIdx.x * 256 + threadIdx.x;   // 262144 total
    const int i = idx >> 9, j = idx & 511;
    Mb[idx]  = (j <= i) ? f2bf(triM[idx]) : (unsigned short)0;
    W1b[idx] = f2bf(d1w[idx]);
    W2b[idx] = f2bf(d2w[idx]);
    return;
  }
  // ln1 stats: per-(batch,split) partials, NO atomics, NO memset dependency
  const int bb = blockIdx.x - 1024;               // = b*16 + s
  const int b = bb >> 4, s = bb & 15;
  const float4* p = (const float4*)(x + (size_t)b * TC_) + (size_t)s * 4096;
  float s1 = 0.f, s2 = 0.f;
  for (int i = threadIdx.x; i < 4096; i += 256) {
    float4 v = p[i];
    s1 += v.x + v.y + v.z + v.w;
    s2 += v.x * v.x + v.y * v.y + v.z * v.z + v.w * v.w;
  }
#pragma unroll
  for (int o = 32; o; o >>= 1) { s1 += __shfl_down(s1, o, 64); s2 += __shfl_down(s2, o, 64); }
  __shared__ float sm[8];
  const int w = threadIdx.x >> 6, lane = threadIdx.x & 63;
  if (lane == 0) { sm[w * 2] = s1; sm[w * 2 + 1] = s2; }
  __syncthreads();
  if (threadIdx.x == 0) {
    float a = 0.f, c = 0.f;
    for (int i = 0; i < 4; ++i) { a += sm[2 * i]; c += sm[2 * i + 1]; }
    red1p[bb * 2] = a;
    red1p[bb * 2 + 1] = c;
  }
}

// ------------- ln1 normalize + transposed bf16 write -------------
__global__ __launch_bounds__(256) void ln1_norm_t(
    const float* __restrict__ x, const float* __restrict__ w,
    const float* __restrict__ bvec, const float* __restrict__ red1p,
    unsigned short* __restrict__ XnT) {
  __shared__ unsigned short tile[64][65];
  const int b = blockIdx.z;
  const int t0 = blockIdx.y * 64;
  const int c0 = blockIdx.x * 64;
  float s1 = 0.f, s2 = 0.f;
#pragma unroll
  for (int i = 0; i < 16; ++i) {
    s1 += red1p[(b * 16 + i) * 2];
    s2 += red1p[(b * 16 + i) * 2 + 1];
  }
  const float mu = s1 * (1.f / TC_);
  const float rstd = rsqrtf(s2 * (1.f / TC_) - mu * mu + 1e-5f);
  const int tid = threadIdx.x;
  const int r = tid >> 4;            // 0..15
  const int cg = (tid & 15) * 4;     // 0..60
#pragma unroll
  for (int rr = 0; rr < 4; ++rr) {
    const int t = t0 + rr * 16 + r;
    const float4 xv = *(const float4*)&x[((size_t)b * T_ + t) * C_ + c0 + cg];
    const float4 wv = *(const float4*)&w[(size_t)t * C_ + c0 + cg];
    const float4 bv = *(const float4*)&bvec[(size_t)t * C_ + c0 + cg];
    tile[rr * 16 + r][cg + 0] = f2bf((xv.x - mu) * rstd * wv.x + bv.x);
    tile[rr * 16 + r][cg + 1] = f2bf((xv.y - mu) * rstd * wv.y + bv.y);
    tile[rr * 16 + r][cg + 2] = f2bf((xv.z - mu) * rstd * wv.z + bv.z);
    tile[rr * 16 + r][cg + 3] = f2bf((xv.w - mu) * rstd * wv.w + bv.w);
  }
  __syncthreads();
  const int cl = tid >> 2;           // 0..63
  const int tg = (tid & 3) * 16;     // 0,16,32,48
  alignas(16) unsigned short tmp[16];
#pragma unroll
  for (int j = 0; j < 16; ++j) tmp[j] = tile[tg + j][cl];
  unsigned short* o = &XnT[((size_t)b * C_ + c0 + cl) * T_ + t0 + tg];
  *(uint4*)&o[0] = *(const uint4*)&tmp[0];
  *(uint4*)&o[8] = *(const uint4*)&tmp[8];
}

// ======== 128x128 GEMM mainloop, BK=128, single 64 KB buffer, reg-prefetch ========
// A rows = C rows (at i0), B rows = C cols (at n0); both ld = 512 shorts.
// LDS tile [128 rows][128 shorts = 16 chunks of 16B].  Physical chunk p of
// row holds logical chunk p ^ (row & 15) (quarter-wave fragment reads cover
// all 16 slots -> free 2-way).  Prologue: global_load_lds (linear dest,
// inverse-permuted source).  Steady state: next tile -> 8 uint4 regs before
// MFMA; written to LDS after the post-MFMA barrier.
__device__ __forceinline__ void gemm_mainloop_bk128(
    const unsigned short* __restrict__ Ag, const unsigned short* __restrict__ Bg,
    int ktiles,                              // 1..4 (any count)
    unsigned short* As, unsigned short* Bs, f32x4 acc[4][2], int tid) {
  const int lane = tid & 63, w = tid >> 6;
  const int wm = w >> 2, wn = w & 3;         // 2 x 4 wave grid
  const int m16 = lane & 15, quad = lane >> 4;
  const int arow = (wm * 64 + m16) * 128;    // shorts (row stride 128)
  const int brow = (wn * 32 + m16) * 128;
  // stage geometry: 2048 chunks per operand = 512 thr x 4; A and B share offs
  int goff[4];                               // global offset (shorts)
#pragma unroll
  for (int j = 0; j < 4; ++j) {
    const int c = tid + 512 * j;
    const int row = c >> 4;                  // 16 chunks per row
    goff[j] = (row << 9) + (((c & 15) ^ (row & 15)) * 8);
  }
  // prologue: tile 0 via global_load_lds
#pragma unroll
  for (int j = 0; j < 4; ++j) {
    const int c = tid + 512 * j;
    load16_lds(Ag + goff[j], As + c * 8);
    load16_lds(Bg + goff[j], Bs + c * 8);
  }
  __syncthreads();
  uint4 rA[4], rB[4];
  for (int kt = 0; kt < ktiles; ++kt) {
    const int k1 = (kt + 1) * 128;
    if (kt + 1 < ktiles) {                   // issue next-tile loads -> regs
#pragma unroll
      for (int j = 0; j < 4; ++j) {
        rA[j] = *(const uint4*)(Ag + goff[j] + k1);
        rB[j] = *(const uint4*)(Bg + goff[j] + k1);
      }
    }
    // compute current tile: 4 k-slices x (4 M x 2 N) 16x16x32
#pragma unroll
    for (int ks = 0; ks < 4; ++ks) {
      const int co = (((ks * 4 + quad) ^ m16) * 8);
      bf16x8 af[4], bfr[2];
#pragma unroll
      for (int m = 0; m < 4; ++m)
        af[m] = *(const bf16x8*)&As[arow + m * 2048 + co];
#pragma unroll
      for (int n = 0; n < 2; ++n)
        bfr[n] = *(const bf16x8*)&Bs[brow + n * 2048 + co];
      __builtin_amdgcn_s_setprio(1);
#pragma unroll
      for (int m = 0; m < 4; ++m)
#pragma unroll
        for (int n = 0; n < 2; ++n)
          acc[m][n] = __builtin_amdgcn_mfma_f32_16x16x32_bf16(af[m], bfr[n], acc[m][n], 0, 0, 0);
      __builtin_amdgcn_s_setprio(0);
    }
    __syncthreads();           // all LDS reads done; reg loads landed
    if (kt + 1 < ktiles) {     // write next tile (linear position c)
#pragma unroll
      for (int j = 0; j < 4; ++j) {
        const int c = tid + 512 * j;
        *(uint4*)(As + c * 8) = rA[j];
        *(uint4*)(Bs + c * 8) = rB[j];
      }
      __syncthreads();         // writes visible before next tile's reads
    }
  }
}

// bijective XCD swizzle for 1024 blocks (1024 % 8 == 0)
__device__ __forceinline__ int xcd_swizzle_1024(int bid) {
  return ((bid & 7) << 7) | (bid >> 3);
}

// ---------------- mixer GEMM: Z = tril(M)@Xn + tri_b + inputs ----------------
__global__ __launch_bounds__(512, 4) void gemm_mixer(
    const unsigned short* __restrict__ Mb, const unsigned short* __restrict__ XnT,
    const float* __restrict__ trib, const float* __restrict__ inp,
    unsigned short* __restrict__ Z, float* __restrict__ red2) {
  __shared__ __align__(16) unsigned short lds[32768];   // 64 KB
  const int swz = xcd_swizzle_1024((int)blockIdx.x);
  const int b = swz >> 4;
  const int i0 = ((swz >> 2) & 3) * 128;
  const int c0 = (swz & 3) * 128;
  f32x4 acc[4][2];
#pragma unroll
  for (int m = 0; m < 4; ++m)
#pragma unroll
    for (int n = 0; n < 2; ++n) acc[m][n] = (f32x4){0.f, 0.f, 0.f, 0.f};
  // tril: rows < i0+128 only need k < i0+128 -> ktiles = i0/128 + 1
  gemm_mainloop_bk128(Mb + (size_t)i0 * T_, XnT + (size_t)b * TC_ + (size_t)c0 * T_,
                      (i0 >> 7) + 1, lds, lds + 16384, acc, (int)threadIdx.x);
  const int tid = threadIdx.x, lane = tid & 63, w = tid >> 6;
  const int wm = w >> 2, wn = w & 3, m16 = lane & 15, quad = lane >> 4;
  const int rbase = i0 + wm * 64, cbase = c0 + wn * 32;
  float s1 = 0.f, s2 = 0.f;
#pragma unroll
  for (int m = 0; m < 4; ++m) {
#pragma unroll
    for (int g = 0; g < 4; ++g) {
      const int i = rbase + m * 16 + quad * 4 + g;
      const float tb = trib[i];
      const float* inrow = &inp[((size_t)b * T_ + i) * C_];
      unsigned short* zrow = &Z[((size_t)b * T_ + i) * C_];
#pragma unroll
      for (int n = 0; n < 2; ++n) {
        const int ch = cbase + n * 16 + m16;
        const float v = acc[m][n][g] + tb + inrow[ch];
        zrow[ch] = f2bf(v);
        s1 += v; s2 += v * v;
      }
    }
  }
#pragma unroll
  for (int o = 32; o; o >>= 1) { s1 += __shfl_down(s1, o, 64); s2 += __shfl_down(s2, o, 64); }
  __shared__ float smf[16];
  if (lane == 0) { smf[w * 2] = s1; smf[w * 2 + 1] = s2; }
  __syncthreads();
  if (tid == 0) {
    float a = 0.f, c2 = 0.f;
    for (int i = 0; i < 8; ++i) { a += smf[2 * i]; c2 += smf[2 * i + 1]; }
    atomicAdd(&red2[b * 2], a);
    atomicAdd(&red2[b * 2 + 1], c2);
  }
}

// ---------------- ln2 normalize ----------------
__global__ __launch_bounds__(256) void ln2_norm(
    const unsigned short* __restrict__ Z, const float* __restrict__ red2,
    const float* __restrict__ w, const float* __restrict__ bvec,
    unsigned short* __restrict__ X2) {
  const size_t e = ((size_t)blockIdx.x * 256 + threadIdx.x) * 8;
  const int b = (int)(e >> 18);
  const int tc = (int)(e & (TC_ - 1));
  const float mu = red2[b * 2] * (1.f / TC_);
  const float rstd = rsqrtf(red2[b * 2 + 1] * (1.f / TC_) - mu * mu + 1e-5f);
  uint4 zp = *(const uint4*)&Z[e];
  const unsigned short* zs = (const unsigned short*)&zp;
  alignas(16) float wv[8], bb[8];
  *(float4*)&wv[0] = *(const float4*)&w[tc];
  *(float4*)&wv[4] = *(const float4*)&w[tc + 4];
  *(float4*)&bb[0] = *(const float4*)&bvec[tc];
  *(float4*)&bb[4] = *(const float4*)&bvec[tc + 4];
  alignas(16) unsigned short o[8];
#pragma unroll
  for (int j = 0; j < 8; ++j)
    o[j] = f2bf((bf2f(zs[j]) - mu) * rstd * wv[j] + bb[j]);
  *(uint4*)&X2[e] = *(const uint4*)&o[0];
}

// ---------------- MLP GEMM 1: H = gelu(X2 @ W1^T + b1) ----------------
__global__ __launch_bounds__(512, 4) void gemm_d1(
    const unsigned short* __restrict__ X2, const unsigned short* __restrict__ W1b,
    const float* __restrict__ d1b, unsigned short* __restrict__ H) {
  __shared__ __align__(16) unsigned short lds[32768];
  const int swz = xcd_swizzle_1024((int)blockIdx.x);
  const int i0 = (swz & 255) * 128;
  const int n0 = (swz >> 8) * 128;
  f32x4 acc[4][2];
#pragma unroll
  for (int m = 0; m < 4; ++m)
#pragma unroll
    for (int n = 0; n < 2; ++n) acc[m][n] = (f32x4){0.f, 0.f, 0.f, 0.f};
  gemm_mainloop_bk128(X2 + (size_t)i0 * C_, W1b + (size_t)n0 * C_, 4,
                      lds, lds + 16384, acc, (int)threadIdx.x);
  const int tid = threadIdx.x, lane = tid & 63, w = tid >> 6;
  const int wm = w >> 2, wn = w & 3, m16 = lane & 15, quad = lane >> 4;
  const int rbase = i0 + wm * 64, cbase = n0 + wn * 32;
#pragma unroll
  for (int m = 0; m < 4; ++m) {
#pragma unroll
    for (int g = 0; g < 4; ++g) {
      const int row = rbase + m * 16 + quad * 4 + g;
#pragma unroll
      for (int n = 0; n < 2; ++n) {
        const int col = cbase + n * 16 + m16;
        const float v = acc[m][n][g] + d1b[col];
        const float gl = 0.5f * v * (1.0f + erff(v * 0.70710678118654752f));
        H[(size_t)row * C_ + col] = f2bf(gl);
      }
    }
  }
}

// ---------------- MLP GEMM 2: out = X2 + H @ W2^T + b2 ----------------
__global__ __launch_bounds__(512, 4) void gemm_d2(
    const unsigned short* __restrict__ H, const unsigned short* __restrict__ W2b,
    const float* __restrict__ d2b, const unsigned short* __restrict__ X2,
    float* __restrict__ out) {
  __shared__ __align__(16) unsigned short lds[32768];
  const int swz = xcd_swizzle_1024((int)blockIdx.x);
  const int i0 = (swz & 255) * 128;
  const int n0 = (swz >> 8) * 128;
  f32x4 acc[4][2];
#pragma unroll
  for (int m = 0; m < 4; ++m)
#pragma unroll
    for (int n = 0; n < 2; ++n) acc[m][n] = (f32x4){0.f, 0.f, 0.f, 0.f};
  gemm_mainloop_bk128(H + (size_t)i0 * C_, W2b + (size_t)n0 * C_, 4,
                      lds, lds + 16384, acc, (int)threadIdx.x);
  const int tid = threadIdx.x, lane = tid & 63, w = tid >> 6;
  const int wm = w >> 2, wn = w & 3, m16 = lane & 15, quad = lane >> 4;
  const int rbase = i0 + wm * 64, cbase = n0 + wn * 32;
#pragma unroll
  for (int m = 0; m < 4; ++m) {
#pragma unroll
    for (int g = 0; g < 4; ++g) {
      const int row = rbase + m * 16 + quad * 4 + g;
#pragma unroll
      for (int n = 0; n < 2; ++n) {
        const int col = cbase + n * 16 + m16;
        out[(size_t)row * C_ + col] =
            acc[m][n][g] + d2b[col] + bf2f(X2[(size_t)row * C_ + col]);
      }
    }
  }
}

extern "C" void kernel_launch(void* const* d_in, const int* in_sizes, int n_in,
                              void* d_out, int out_size, void* d_ws, size_t ws_size,
                              hipStream_t stream) {
  const float* inp  = (const float*)d_in[0];
  const float* ln1w = (const float*)d_in[1];
  const float* ln1b = (const float*)d_in[2];
  const float* ln2w = (const float*)d_in[3];
  const float* ln2b = (const float*)d_in[4];
  const float* triM = (const float*)d_in[5];
  const float* trib = (const float*)d_in[6];
  const float* d1w  = (const float*)d_in[7];
  const float* d1b  = (const float*)d_in[8];
  const float* d2w  = (const float*)d_in[9];
  const float* d2b  = (const float*)d_in[10];
  float* out = (float*)d_out;

  char* ws = (char*)d_ws;
  float* red1p = (float*)ws;                        // 1024*2 floats (8 KB)
  float* red2  = (float*)(ws + 8192);               // 64*2 floats
  unsigned short* Mb  = (unsigned short*)(ws + 16384);
  unsigned short* W1b = Mb + TC_;
  unsigned short* W2b = W1b + TC_;
  unsigned short* XnT = W2b + TC_;                  // [B][C][T] bf16
  unsigned short* Z   = XnT + (size_t)B_ * TC_;     // [B][T][C] bf16
  unsigned short* X2  = Z + (size_t)B_ * TC_;       // [B][T][C] bf16
  unsigned short* H   = X2 + (size_t)B_ * TC_;      // [B*T][C] bf16

  prep<<<2048, 256, 0, stream>>>(triM, d1w, d2w, Mb, W1b, W2b, inp, red1p, red2);
  ln1_norm_t<<<dim3(8, 8, B_), 256, 0, stream>>>(inp, ln1w, ln1b, red1p, XnT);
  gemm_mixer<<<1024, 512, 0, stream>>>(Mb, XnT, trib, inp, Z, red2);
  ln2_norm<<<8192, 256, 0, stream>>>(Z, red2, ln2w, ln2b, X2);
  gemm_d1<<<1024, 512, 0, stream>>>(X2, W1b, d1b, H);
  gemm_d2<<<1024, 512, 0, stream>>>(H, W2b, d2b, X2, out);
}

// Round 13
// 277.493 us; speedup vs baseline: 1.4741x; 1.4741x over previous
//
#include <hip/hip_runtime.h>
#include <hip/hip_bf16.h>
#include <math.h>

// Mixer2dTriU: B=64, T=512, C=512, fp32 in/out.
// 6 dispatches (r11 structure, 248 us proven):
//   prep / ln1_norm_t / gemm_mixer / ln2_norm / gemm_d1 / gemm_d2
//
// r12 post-mortem: reg-prefetch ACROSS a barrier spills (compiler demotes the
// held uint4s to scratch; WRITE_SIZE 32->257 MB).  r13 keeps BK=128 (4
// K-iterations -- the proven lever) with NO registers held across barriers:
//   d1/d2: A staged in LDS (128x128 bf16 DOUBLE-buffered = 64 KB, proven
//   size) via global_load_lds; B = W1/W2 (0.5 MB, L2-resident) read as MFMA
//   fragments DIRECT from global into regs, consumed in-iteration.
//   Issue order per iter: B frags first, then A(kt+1) stage -> the MFMA's
//   vmcnt wait for B does not drain A (in-order counter); A drains at the
//   single post-MFMA barrier, covered by B-latency + MFMA cluster.
// (r8's B-from-L2 failure streamed the whole 1 MB W per 32-row block = 1 GB
//  L2 traffic; here each block gathers its 128 KB panel once = 128 MB.)
// Mixer keeps the r11 BK=64 LDS loop (its B = XnT is not L2-resident).
// Swizzle (A, 16 chunks/row): phys = logical ^ (row&15), r12-verified
// mapping.  setprio, bijective XCD swizzle, __launch_bounds__(512,4).
// Spill canary: d1/d2 WRITE_SIZE must stay 32768 KB.

#define B_ 64
#define T_ 512
#define C_ 512
#define TC_ (T_ * C_)
static_assert(TC_ == 262144, "");

typedef __attribute__((ext_vector_type(8))) short bf16x8;
typedef __attribute__((ext_vector_type(4))) float f32x4;

__device__ __forceinline__ unsigned short f2bf(float f) {
  union { float f; unsigned u; } v; v.f = f;
  unsigned r = v.u + 0x7FFF + ((v.u >> 16) & 1);   // RNE
  return (unsigned short)(r >> 16);
}
__device__ __forceinline__ float bf2f(unsigned short h) {
  union { unsigned u; float f; } v; v.u = ((unsigned)h) << 16; return v.f;
}

// async global -> LDS, 16 B per lane (global_load_lds_dwordx4)
__device__ __forceinline__ void load16_lds(const void* gsrc, void* ldst) {
  __builtin_amdgcn_global_load_lds(
      (const __attribute__((address_space(1))) unsigned int*)gsrc,
      (__attribute__((address_space(3))) unsigned int*)ldst,
      16, 0, 0);
}

// ------------- prep: weights->bf16 + ln1 partial stats + zero red2 -------------
__global__ __launch_bounds__(256) void prep(
    const float* __restrict__ triM, const float* __restrict__ d1w,
    const float* __restrict__ d2w, unsigned short* __restrict__ Mb,
    unsigned short* __restrict__ W1b, unsigned short* __restrict__ W2b,
    const float* __restrict__ x, float* __restrict__ red1p,
    float* __restrict__ red2) {
  if (blockIdx.x < 1024) {
    if (blockIdx.x == 0 && threadIdx.x < 128) red2[threadIdx.x] = 0.f;
    const int idx = blockIdx.x * 256 + threadIdx.x;   // 262144 total
    const int i = idx >> 9, j = idx & 511;
    Mb[idx]  = (j <= i) ? f2bf(triM[idx]) : (unsigned short)0;
    W1b[idx] = f2bf(d1w[idx]);
    W2b[idx] = f2bf(d2w[idx]);
    return;
  }
  // ln1 stats: per-(batch,split) partials, NO atomics, NO memset dependency
  const int bb = blockIdx.x - 1024;               // = b*16 + s
  const int b = bb >> 4, s = bb & 15;
  const float4* p = (const float4*)(x + (size_t)b * TC_) + (size_t)s * 4096;
  float s1 = 0.f, s2 = 0.f;
  for (int i = threadIdx.x; i < 4096; i += 256) {
    float4 v = p[i];
    s1 += v.x + v.y + v.z + v.w;
    s2 += v.x * v.x + v.y * v.y + v.z * v.z + v.w * v.w;
  }
#pragma unroll
  for (int o = 32; o; o >>= 1) { s1 += __shfl_down(s1, o, 64); s2 += __shfl_down(s2, o, 64); }
  __shared__ float sm[8];
  const int w = threadIdx.x >> 6, lane = threadIdx.x & 63;
  if (lane == 0) { sm[w * 2] = s1; sm[w * 2 + 1] = s2; }
  __syncthreads();
  if (threadIdx.x == 0) {
    float a = 0.f, c = 0.f;
    for (int i = 0; i < 4; ++i) { a += sm[2 * i]; c += sm[2 * i + 1]; }
    red1p[bb * 2] = a;
    red1p[bb * 2 + 1] = c;
  }
}

// ------------- ln1 normalize + transposed bf16 write -------------
__global__ __launch_bounds__(256) void ln1_norm_t(
    const float* __restrict__ x, const float* __restrict__ w,
    const float* __restrict__ bvec, const float* __restrict__ red1p,
    unsigned short* __restrict__ XnT) {
  __shared__ unsigned short tile[64][65];
  const int b = blockIdx.z;
  const int t0 = blockIdx.y * 64;
  const int c0 = blockIdx.x * 64;
  float s1 = 0.f, s2 = 0.f;
#pragma unroll
  for (int i = 0; i < 16; ++i) {
    s1 += red1p[(b * 16 + i) * 2];
    s2 += red1p[(b * 16 + i) * 2 + 1];
  }
  const float mu = s1 * (1.f / TC_);
  const float rstd = rsqrtf(s2 * (1.f / TC_) - mu * mu + 1e-5f);
  const int tid = threadIdx.x;
  const int r = tid >> 4;            // 0..15
  const int cg = (tid & 15) * 4;     // 0..60
#pragma unroll
  for (int rr = 0; rr < 4; ++rr) {
    const int t = t0 + rr * 16 + r;
    const float4 xv = *(const float4*)&x[((size_t)b * T_ + t) * C_ + c0 + cg];
    const float4 wv = *(const float4*)&w[(size_t)t * C_ + c0 + cg];
    const float4 bv = *(const float4*)&bvec[(size_t)t * C_ + c0 + cg];
    tile[rr * 16 + r][cg + 0] = f2bf((xv.x - mu) * rstd * wv.x + bv.x);
    tile[rr * 16 + r][cg + 1] = f2bf((xv.y - mu) * rstd * wv.y + bv.y);
    tile[rr * 16 + r][cg + 2] = f2bf((xv.z - mu) * rstd * wv.z + bv.z);
    tile[rr * 16 + r][cg + 3] = f2bf((xv.w - mu) * rstd * wv.w + bv.w);
  }
  __syncthreads();
  const int cl = tid >> 2;           // 0..63
  const int tg = (tid & 3) * 16;     // 0,16,32,48
  alignas(16) unsigned short tmp[16];
#pragma unroll
  for (int j = 0; j < 16; ++j) tmp[j] = tile[tg + j][cl];
  unsigned short* o = &XnT[((size_t)b * C_ + c0 + cl) * T_ + t0 + tg];
  *(uint4*)&o[0] = *(const uint4*)&tmp[0];
  *(uint4*)&o[8] = *(const uint4*)&tmp[8];
}

// ============ 128x128 GEMM mainloop, BK=64, 8 waves, 64 KB dbuf (r11-proven) ============
__device__ __forceinline__ void stage_tile64(
    const unsigned short* __restrict__ Ag, const unsigned short* __restrict__ Bg,
    int k0, unsigned short* As, unsigned short* Bs, int tid) {
#pragma unroll
  for (int j = 0; j < 2; ++j) {
    const int c = tid + 512 * j;               // 0..1023, 16B chunks
    const int row = c >> 3;
    const int l = ((c & 7) ^ (row & 7)) * 8;   // swizzled k-offset (shorts)
    load16_lds(Ag + ((size_t)row << 9) + k0 + l, As + c * 8);
    load16_lds(Bg + ((size_t)row << 9) + k0 + l, Bs + c * 8);
  }
}

__device__ __forceinline__ void mfma_tile64(
    const unsigned short* __restrict__ As, const unsigned short* __restrict__ Bs,
    int arow, int brow, int quad, int xk, f32x4 acc[4][2]) {
#pragma unroll
  for (int ks = 0; ks < 2; ++ks) {
    const int co = (((ks * 4 + quad) ^ xk) * 8);
    bf16x8 af[4], bfr[2];
#pragma unroll
    for (int m = 0; m < 4; ++m)
      af[m] = *(const bf16x8*)&As[arow + m * 1024 + co];
#pragma unroll
    for (int n = 0; n < 2; ++n)
      bfr[n] = *(const bf16x8*)&Bs[brow + n * 1024 + co];
    __builtin_amdgcn_s_setprio(1);
#pragma unroll
    for (int m = 0; m < 4; ++m)
#pragma unroll
      for (int n = 0; n < 2; ++n)
        acc[m][n] = __builtin_amdgcn_mfma_f32_16x16x32_bf16(af[m], bfr[n], acc[m][n], 0, 0, 0);
    __builtin_amdgcn_s_setprio(0);
  }
}

__device__ __forceinline__ void gemm_mainloop64(
    const unsigned short* __restrict__ Ag, const unsigned short* __restrict__ Bg,
    int ktiles,                               // even (2..8)
    unsigned short* lds, f32x4 acc[4][2], int tid) {
  const int lane = tid & 63;
  const int w = tid >> 6;
  const int wm = w >> 2, wn = w & 3;          // 2 x 4 wave grid
  const int m16 = lane & 15, quad = lane >> 4;
  unsigned short* A0 = lds;                   // 16 KB each
  unsigned short* B0 = lds + 8192;
  unsigned short* A1 = lds + 16384;
  unsigned short* B1 = lds + 24576;
  const int arow = (wm * 64 + m16) * 64;      // shorts (row stride 64)
  const int brow = (wn * 32 + m16) * 64;
  const int xk = m16 & 7;                     // read-side xor key
  stage_tile64(Ag, Bg, 0, A0, B0, tid);       // prologue: tile 0
  __syncthreads();
  for (int kt = 0; kt < ktiles; kt += 2) {
    stage_tile64(Ag, Bg, (kt + 1) * 64, A1, B1, tid);
    mfma_tile64(A0, B0, arow, brow, quad, xk, acc);
    __syncthreads();
    if (kt + 2 < ktiles)
      stage_tile64(Ag, Bg, (kt + 2) * 64, A0, B0, tid);
    mfma_tile64(A1, B1, arow, brow, quad, xk, acc);
    __syncthreads();
  }
}

// ==== 128x128 GEMM, BK=128: A in LDS dbuf (64 KB), B frags direct from L2 ====
// A rows at i0 (ld=512).  Bg = W panel at row n0 (ld=512), L2-resident.
// A LDS tile [128 rows][128 shorts = 16 chunks]; phys chunk = logical ^
// (row&15) (r12-verified mapping).  Per iter: B frags -> regs FIRST, then
// A(kt+1) global_load_lds (issue order => MFMA's B-wait does not drain A),
// MFMA cluster, ONE barrier.  B regs consumed in-iteration (no spill path).
__device__ __forceinline__ void gemm_bk128_breg(
    const unsigned short* __restrict__ Ag, const unsigned short* __restrict__ Bg,
    int ktiles,                              // K/128 (= 4)
    unsigned short* As,                      // 2 x 16384 shorts
    f32x4 acc[4][2], int tid) {
  const int lane = tid & 63, w = tid >> 6;
  const int wm = w >> 2, wn = w & 3;         // 2 x 4 wave grid
  const int m16 = lane & 15, quad = lane >> 4;
  const int arow = (wm * 64 + m16) * 128;    // shorts (row stride 128)
  const unsigned short* brow0 = Bg + (size_t)(wn * 32 + m16) * 512;
  const unsigned short* brow1 = Bg + (size_t)(wn * 32 + 16 + m16) * 512;
  // A stage geometry: 2048 chunks = 512 thr x 4
  int gofs[4];
#pragma unroll
  for (int j = 0; j < 4; ++j) {
    const int c = tid + 512 * j;
    const int row = c >> 4;                  // 16 chunks per row
    gofs[j] = (row << 9) + (((c & 15) ^ (row & 15)) * 8);
  }
  // prologue: A tile 0
#pragma unroll
  for (int j = 0; j < 4; ++j)
    load16_lds(Ag + gofs[j], As + (tid + 512 * j) * 8);
  __syncthreads();
  for (int kt = 0; kt < ktiles; ++kt) {
    unsigned short* Ac = As + (kt & 1) * 16384;
    unsigned short* An = As + ((kt + 1) & 1) * 16384;
    // B fragments for THIS tile -> regs (L2-hot; issued before A stage)
    bf16x8 bf[4][2];
    const int kb = kt * 128;
#pragma unroll
    for (int ks = 0; ks < 4; ++ks) {
      bf[ks][0] = *(const bf16x8*)&brow0[kb + ks * 32 + quad * 8];
      bf[ks][1] = *(const bf16x8*)&brow1[kb + ks * 32 + quad * 8];
    }
    if (kt + 1 < ktiles) {                   // A stage AFTER B issue
#pragma unroll
      for (int j = 0; j < 4; ++j)
        load16_lds(Ag + (kt + 1) * 128 + gofs[j], An + (tid + 512 * j) * 8);
    }
#pragma unroll
    for (int ks = 0; ks < 4; ++ks) {
      const int co = (((ks * 4 + quad) ^ m16) * 8);
      bf16x8 af[4];
#pragma unroll
      for (int m = 0; m < 4; ++m)
        af[m] = *(const bf16x8*)&Ac[arow + m * 2048 + co];
      __builtin_amdgcn_s_setprio(1);
#pragma unroll
      for (int m = 0; m < 4; ++m)
#pragma unroll
        for (int n = 0; n < 2; ++n)
          acc[m][n] = __builtin_amdgcn_mfma_f32_16x16x32_bf16(af[m], bf[ks][n], acc[m][n], 0, 0, 0);
      __builtin_amdgcn_s_setprio(0);
    }
    __syncthreads();                         // drains A(kt+1); reads of Ac done
  }
}

// bijective XCD swizzle for 1024 blocks (1024 % 8 == 0)
__device__ __forceinline__ int xcd_swizzle_1024(int bid) {
  return ((bid & 7) << 7) | (bid >> 3);
}

// ---------------- mixer GEMM: Z = tril(M)@Xn + tri_b + inputs ----------------
__global__ __launch_bounds__(512, 4) void gemm_mixer(
    const unsigned short* __restrict__ Mb, const unsigned short* __restrict__ XnT,
    const float* __restrict__ trib, const float* __restrict__ inp,
    unsigned short* __restrict__ Z, float* __restrict__ red2) {
  __shared__ __align__(16) unsigned short lds[32768];   // 64 KB
  const int swz = xcd_swizzle_1024((int)blockIdx.x);
  const int b = swz >> 4;
  const int i0 = ((swz >> 2) & 3) * 128;
  const int c0 = (swz & 3) * 128;
  f32x4 acc[4][2];
#pragma unroll
  for (int m = 0; m < 4; ++m)
#pragma unroll
    for (int n = 0; n < 2; ++n) acc[m][n] = (f32x4){0.f, 0.f, 0.f, 0.f};
  // tril: rows < i0+128 only need k < i0+128 -> ktiles = (i0+128)/64 (even)
  gemm_mainloop64(Mb + (size_t)i0 * T_, XnT + (size_t)b * TC_ + (size_t)c0 * T_,
                  (i0 >> 6) + 2, lds, acc, (int)threadIdx.x);
  const int tid = threadIdx.x, lane = tid & 63, w = tid >> 6;
  const int wm = w >> 2, wn = w & 3, m16 = lane & 15, quad = lane >> 4;
  const int rbase = i0 + wm * 64, cbase = c0 + wn * 32;
  float s1 = 0.f, s2 = 0.f;
#pragma unroll
  for (int m = 0; m < 4; ++m) {
#pragma unroll
    for (int g = 0; g < 4; ++g) {
      const int i = rbase + m * 16 + quad * 4 + g;
      const float tb = trib[i];
      const float* inrow = &inp[((size_t)b * T_ + i) * C_];
      unsigned short* zrow = &Z[((size_t)b * T_ + i) * C_];
#pragma unroll
      for (int n = 0; n < 2; ++n) {
        const int ch = cbase + n * 16 + m16;
        const float v = acc[m][n][g] + tb + inrow[ch];
        zrow[ch] = f2bf(v);
        s1 += v; s2 += v * v;
      }
    }
  }
#pragma unroll
  for (int o = 32; o; o >>= 1) { s1 += __shfl_down(s1, o, 64); s2 += __shfl_down(s2, o, 64); }
  __shared__ float smf[16];
  if (lane == 0) { smf[w * 2] = s1; smf[w * 2 + 1] = s2; }
  __syncthreads();
  if (tid == 0) {
    float a = 0.f, c2 = 0.f;
    for (int i = 0; i < 8; ++i) { a += smf[2 * i]; c2 += smf[2 * i + 1]; }
    atomicAdd(&red2[b * 2], a);
    atomicAdd(&red2[b * 2 + 1], c2);
  }
}

// ---------------- ln2 normalize ----------------
__global__ __launch_bounds__(256) void ln2_norm(
    const unsigned short* __restrict__ Z, const float* __restrict__ red2,
    const float* __restrict__ w, const float* __restrict__ bvec,
    unsigned short* __restrict__ X2) {
  const size_t e = ((size_t)blockIdx.x * 256 + threadIdx.x) * 8;
  const int b = (int)(e >> 18);
  const int tc = (int)(e & (TC_ - 1));
  const float mu = red2[b * 2] * (1.f / TC_);
  const float rstd = rsqrtf(red2[b * 2 + 1] * (1.f / TC_) - mu * mu + 1e-5f);
  uint4 zp = *(const uint4*)&Z[e];
  const unsigned short* zs = (const unsigned short*)&zp;
  alignas(16) float wv[8], bb[8];
  *(float4*)&wv[0] = *(const float4*)&w[tc];
  *(float4*)&wv[4] = *(const float4*)&w[tc + 4];
  *(float4*)&bb[0] = *(const float4*)&bvec[tc];
  *(float4*)&bb[4] = *(const float4*)&bvec[tc + 4];
  alignas(16) unsigned short o[8];
#pragma unroll
  for (int j = 0; j < 8; ++j)
    o[j] = f2bf((bf2f(zs[j]) - mu) * rstd * wv[j] + bb[j]);
  *(uint4*)&X2[e] = *(const uint4*)&o[0];
}

// ---------------- MLP GEMM 1: H = gelu(X2 @ W1^T + b1) ----------------
__global__ __launch_bounds__(512, 4) void gemm_d1(
    const unsigned short* __restrict__ X2, const unsigned short* __restrict__ W1b,
    const float* __restrict__ d1b, unsigned short* __restrict__ H) {
  __shared__ __align__(16) unsigned short lds[32768];   // 64 KB (A dbuf)
  const int swz = xcd_swizzle_1024((int)blockIdx.x);
  const int i0 = (swz & 255) * 128;
  const int n0 = (swz >> 8) * 128;
  f32x4 acc[4][2];
#pragma unroll
  for (int m = 0; m < 4; ++m)
#pragma unroll
    for (int n = 0; n < 2; ++n) acc[m][n] = (f32x4){0.f, 0.f, 0.f, 0.f};
  gemm_bk128_breg(X2 + (size_t)i0 * C_, W1b + (size_t)n0 * C_, 4, lds, acc,
                  (int)threadIdx.x);
  const int tid = threadIdx.x, lane = tid & 63, w = tid >> 6;
  const int wm = w >> 2, wn = w & 3, m16 = lane & 15, quad = lane >> 4;
  const int rbase = i0 + wm * 64, cbase = n0 + wn * 32;
#pragma unroll
  for (int m = 0; m < 4; ++m) {
#pragma unroll
    for (int g = 0; g < 4; ++g) {
      const int row = rbase + m * 16 + quad * 4 + g;
#pragma unroll
      for (int n = 0; n < 2; ++n) {
        const int col = cbase + n * 16 + m16;
        const float v = acc[m][n][g] + d1b[col];
        const float gl = 0.5f * v * (1.0f + erff(v * 0.70710678118654752f));
        H[(size_t)row * C_ + col] = f2bf(gl);
      }
    }
  }
}

// ---------------- MLP GEMM 2: out = X2 + H @ W2^T + b2 ----------------
__global__ __launch_bounds__(512, 4) void gemm_d2(
    const unsigned short* __restrict__ H, const unsigned short* __restrict__ W2b,
    const float* __restrict__ d2b, const unsigned short* __restrict__ X2,
    float* __restrict__ out) {
  __shared__ __align__(16) unsigned short lds[32768];
  const int swz = xcd_swizzle_1024((int)blockIdx.x);
  const int i0 = (swz & 255) * 128;
  const int n0 = (swz >> 8) * 128;
  f32x4 acc[4][2];
#pragma unroll
  for (int m = 0; m < 4; ++m)
#pragma unroll
    for (int n = 0; n < 2; ++n) acc[m][n] = (f32x4){0.f, 0.f, 0.f, 0.f};
  gemm_bk128_breg(H + (size_t)i0 * C_, W2b + (size_t)n0 * C_, 4, lds, acc,
                  (int)threadIdx.x);
  const int tid = threadIdx.x, lane = tid & 63, w = tid >> 6;
  const int wm = w >> 2, wn = w & 3, m16 = lane & 15, quad = lane >> 4;
  const int rbase = i0 + wm * 64, cbase = n0 + wn * 32;
#pragma unroll
  for (int m = 0; m < 4; ++m) {
#pragma unroll
    for (int g = 0; g < 4; ++g) {
      const int row = rbase + m * 16 + quad * 4 + g;
#pragma unroll
      for (int n = 0; n < 2; ++n) {
        const int col = cbase + n * 16 + m16;
        out[(size_t)row * C_ + col] =
            acc[m][n][g] + d2b[col] + bf2f(X2[(size_t)row * C_ + col]);
      }
    }
  }
}

extern "C" void kernel_launch(void* const* d_in, const int* in_sizes, int n_in,
                              void* d_out, int out_size, void* d_ws, size_t ws_size,
                              hipStream_t stream) {
  const float* inp  = (const float*)d_in[0];
  const float* ln1w = (const float*)d_in[1];
  const float* ln1b = (const float*)d_in[2];
  const float* ln2w = (const float*)d_in[3];
  const float* ln2b = (const float*)d_in[4];
  const float* triM = (const float*)d_in[5];
  const float* trib = (const float*)d_in[6];
  const float* d1w  = (const float*)d_in[7];
  const float* d1b  = (const float*)d_in[8];
  const float* d2w  = (const float*)d_in[9];
  const float* d2b  = (const float*)d_in[10];
  float* out = (float*)d_out;

  char* ws = (char*)d_ws;
  float* red1p = (float*)ws;                        // 1024*2 floats (8 KB)
  float* red2  = (float*)(ws + 8192);               // 64*2 floats
  unsigned short* Mb  = (unsigned short*)(ws + 16384);
  unsigned short* W1b = Mb + TC_;
  unsigned short* W2b = W1b + TC_;
  unsigned short* XnT = W2b + TC_;                  // [B][C][T] bf16
  unsigned short* Z   = XnT + (size_t)B_ * TC_;     // [B][T][C] bf16
  unsigned short* X2  = Z + (size_t)B_ * TC_;       // [B][T][C] bf16
  unsigned short* H   = X2 + (size_t)B_ * TC_;      // [B*T][C] bf16

  prep<<<2048, 256, 0, stream>>>(triM, d1w, d2w, Mb, W1b, W2b, inp, red1p, red2);
  ln1_norm_t<<<dim3(8, 8, B_), 256, 0, stream>>>(inp, ln1w, ln1b, red1p, XnT);
  gemm_mixer<<<1024, 512, 0, stream>>>(Mb, XnT, trib, inp, Z, red2);
  ln2_norm<<<8192, 256, 0, stream>>>(Z, red2, ln2w, ln2b, X2);
  gemm_d1<<<1024, 512, 0, stream>>>(X2, W1b, d1b, H);
  gemm_d2<<<1024, 512, 0, stream>>>(H, W2b, d2b, X2, out);
}

// Round 14
// 258.237 us; speedup vs baseline: 1.5841x; 1.0746x over previous
//
#include <hip/hip_runtime.h>
#include <hip/hip_bf16.h>
#include <math.h>

// Mixer2dTriU: B=64, T=512, C=512, fp32 in/out.
// 6 dispatches (r11 structure, 248 us anchor):
//   prep / ln1_norm_t / gemm_mixer / ln2_norm(in-place) / gemm_d1 / gemm_d2
//
// r14 deltas vs r11 (GEMM geometry byte-identical to r11's proven BK=64,
// 128x128 tile, 8 waves, 64 KB dbuf, 40 VGPR):
//  1. T4 counted-vmcnt mainloop: stage(kt+1) -> s_waitcnt vmcnt(4) (own share
//     of tile kt landed; next tile's 4 loads/wave stay IN FLIGHT across both
//     barriers) -> s_barrier -> MFMA(kt) -> lgkmcnt(0) -> s_barrier.
//     Replaces __syncthreads' vmcnt(0) drain that serialized staging with
//     compute every iteration (catalog m218: counted vs drain0 = +38-73%).
//     Fallback declared: container death => r15 reverts to r11 verbatim.
//  2. d1/d2 XCD mapping: each XCD owns 32 i-tiles x 4 n-tiles -> its X2/H
//     slice is 4 MB = fits the XCD-private L2 (old mapping: 16 MB slice,
//     L3-served staging).
//  3. Aliasing: ln2 is IN-PLACE (X2 == Z, single pointer); H == XnT (dead
//     after mixer).  Keeps d1/d2 operand reads on L3-hot pages.
// Spill canary: d1 WRITE_SIZE must stay 32768 KB.

#define B_ 64
#define T_ 512
#define C_ 512
#define TC_ (T_ * C_)
static_assert(TC_ == 262144, "");

typedef __attribute__((ext_vector_type(8))) short bf16x8;
typedef __attribute__((ext_vector_type(4))) float f32x4;

__device__ __forceinline__ unsigned short f2bf(float f) {
  union { float f; unsigned u; } v; v.f = f;
  unsigned r = v.u + 0x7FFF + ((v.u >> 16) & 1);   // RNE
  return (unsigned short)(r >> 16);
}
__device__ __forceinline__ float bf2f(unsigned short h) {
  union { unsigned u; float f; } v; v.u = ((unsigned)h) << 16; return v.f;
}

// async global -> LDS, 16 B per lane (global_load_lds_dwordx4)
__device__ __forceinline__ void load16_lds(const void* gsrc, void* ldst) {
  __builtin_amdgcn_global_load_lds(
      (const __attribute__((address_space(1))) unsigned int*)gsrc,
      (__attribute__((address_space(3))) unsigned int*)ldst,
      16, 0, 0);
}

// ------------- prep: weights->bf16 + ln1 partial stats + zero red2 -------------
__global__ __launch_bounds__(256) void prep(
    const float* __restrict__ triM, const float* __restrict__ d1w,
    const float* __restrict__ d2w, unsigned short* __restrict__ Mb,
    unsigned short* __restrict__ W1b, unsigned short* __restrict__ W2b,
    const float* __restrict__ x, float* __restrict__ red1p,
    float* __restrict__ red2) {
  if (blockIdx.x < 1024) {
    if (blockIdx.x == 0 && threadIdx.x < 128) red2[threadIdx.x] = 0.f;
    const int idx = blockIdx.x * 256 + threadIdx.x;   // 262144 total
    const int i = idx >> 9, j = idx & 511;
    Mb[idx]  = (j <= i) ? f2bf(triM[idx]) : (unsigned short)0;
    W1b[idx] = f2bf(d1w[idx]);
    W2b[idx] = f2bf(d2w[idx]);
    return;
  }
  // ln1 stats: per-(batch,split) partials, NO atomics, NO memset dependency
  const int bb = blockIdx.x - 1024;               // = b*16 + s
  const int b = bb >> 4, s = bb & 15;
  const float4* p = (const float4*)(x + (size_t)b * TC_) + (size_t)s * 4096;
  float s1 = 0.f, s2 = 0.f;
  for (int i = threadIdx.x; i < 4096; i += 256) {
    float4 v = p[i];
    s1 += v.x + v.y + v.z + v.w;
    s2 += v.x * v.x + v.y * v.y + v.z * v.z + v.w * v.w;
  }
#pragma unroll
  for (int o = 32; o; o >>= 1) { s1 += __shfl_down(s1, o, 64); s2 += __shfl_down(s2, o, 64); }
  __shared__ float sm[8];
  const int w = threadIdx.x >> 6, lane = threadIdx.x & 63;
  if (lane == 0) { sm[w * 2] = s1; sm[w * 2 + 1] = s2; }
  __syncthreads();
  if (threadIdx.x == 0) {
    float a = 0.f, c = 0.f;
    for (int i = 0; i < 4; ++i) { a += sm[2 * i]; c += sm[2 * i + 1]; }
    red1p[bb * 2] = a;
    red1p[bb * 2 + 1] = c;
  }
}

// ------------- ln1 normalize + transposed bf16 write -------------
__global__ __launch_bounds__(256) void ln1_norm_t(
    const float* __restrict__ x, const float* __restrict__ w,
    const float* __restrict__ bvec, const float* __restrict__ red1p,
    unsigned short* __restrict__ XnT) {
  __shared__ unsigned short tile[64][65];
  const int b = blockIdx.z;
  const int t0 = blockIdx.y * 64;
  const int c0 = blockIdx.x * 64;
  float s1 = 0.f, s2 = 0.f;
#pragma unroll
  for (int i = 0; i < 16; ++i) {
    s1 += red1p[(b * 16 + i) * 2];
    s2 += red1p[(b * 16 + i) * 2 + 1];
  }
  const float mu = s1 * (1.f / TC_);
  const float rstd = rsqrtf(s2 * (1.f / TC_) - mu * mu + 1e-5f);
  const int tid = threadIdx.x;
  const int r = tid >> 4;            // 0..15
  const int cg = (tid & 15) * 4;     // 0..60
#pragma unroll
  for (int rr = 0; rr < 4; ++rr) {
    const int t = t0 + rr * 16 + r;
    const float4 xv = *(const float4*)&x[((size_t)b * T_ + t) * C_ + c0 + cg];
    const float4 wv = *(const float4*)&w[(size_t)t * C_ + c0 + cg];
    const float4 bv = *(const float4*)&bvec[(size_t)t * C_ + c0 + cg];
    tile[rr * 16 + r][cg + 0] = f2bf((xv.x - mu) * rstd * wv.x + bv.x);
    tile[rr * 16 + r][cg + 1] = f2bf((xv.y - mu) * rstd * wv.y + bv.y);
    tile[rr * 16 + r][cg + 2] = f2bf((xv.z - mu) * rstd * wv.z + bv.z);
    tile[rr * 16 + r][cg + 3] = f2bf((xv.w - mu) * rstd * wv.w + bv.w);
  }
  __syncthreads();
  const int cl = tid >> 2;           // 0..63
  const int tg = (tid & 3) * 16;     // 0,16,32,48
  alignas(16) unsigned short tmp[16];
#pragma unroll
  for (int j = 0; j < 16; ++j) tmp[j] = tile[tg + j][cl];
  unsigned short* o = &XnT[((size_t)b * C_ + c0 + cl) * T_ + t0 + tg];
  *(uint4*)&o[0] = *(const uint4*)&tmp[0];
  *(uint4*)&o[8] = *(const uint4*)&tmp[8];
}

// ============ 128x128 GEMM mainloop, BK=64, 8 waves, 64 KB dbuf ============
// r11-proven geometry; r14 loop = T4 counted vmcnt (no in-loop vmcnt(0)).
// LDS tile [128 rows][64 shorts]; phys 16B-chunk = logical ^ (row & 7)
// (r6-measured 0 conflicts).  Stage: linear LDS dest, inverse-permuted
// global source (involution).  4 vm-ops per wave per stage -> vmcnt(4).
__device__ __forceinline__ void stage_tile64(
    const unsigned short* __restrict__ Ag, const unsigned short* __restrict__ Bg,
    int k0, unsigned short* As, unsigned short* Bs, int tid) {
#pragma unroll
  for (int j = 0; j < 2; ++j) {
    const int c = tid + 512 * j;               // 0..1023, 16B chunks
    const int row = c >> 3;
    const int l = ((c & 7) ^ (row & 7)) * 8;   // swizzled k-offset (shorts)
    load16_lds(Ag + ((size_t)row << 9) + k0 + l, As + c * 8);
    load16_lds(Bg + ((size_t)row << 9) + k0 + l, Bs + c * 8);
  }
}

__device__ __forceinline__ void mfma_tile64(
    const unsigned short* __restrict__ As, const unsigned short* __restrict__ Bs,
    int arow, int brow, int quad, int xk, f32x4 acc[4][2]) {
#pragma unroll
  for (int ks = 0; ks < 2; ++ks) {
    const int co = (((ks * 4 + quad) ^ xk) * 8);
    bf16x8 af[4], bfr[2];
#pragma unroll
    for (int m = 0; m < 4; ++m)
      af[m] = *(const bf16x8*)&As[arow + m * 1024 + co];
#pragma unroll
    for (int n = 0; n < 2; ++n)
      bfr[n] = *(const bf16x8*)&Bs[brow + n * 1024 + co];
    __builtin_amdgcn_s_setprio(1);
#pragma unroll
    for (int m = 0; m < 4; ++m)
#pragma unroll
      for (int n = 0; n < 2; ++n)
        acc[m][n] = __builtin_amdgcn_mfma_f32_16x16x32_bf16(af[m], bfr[n], acc[m][n], 0, 0, 0);
    __builtin_amdgcn_s_setprio(0);
  }
}

__device__ __forceinline__ void gemm_mainloop64(
    const unsigned short* __restrict__ Ag, const unsigned short* __restrict__ Bg,
    int ktiles,                               // any >= 1
    unsigned short* lds, f32x4 acc[4][2], int tid) {
  const int lane = tid & 63;
  const int w = tid >> 6;
  const int wm = w >> 2, wn = w & 3;          // 2 x 4 wave grid
  const int m16 = lane & 15, quad = lane >> 4;
  unsigned short* A0 = lds;                   // 16 KB each
  unsigned short* B0 = lds + 8192;
  unsigned short* A1 = lds + 16384;
  unsigned short* B1 = lds + 24576;
  const int arow = (wm * 64 + m16) * 64;      // shorts (row stride 64)
  const int brow = (wn * 32 + m16) * 64;
  const int xk = m16 & 7;                     // read-side xor key
  stage_tile64(Ag, Bg, 0, A0, B0, tid);       // prologue: tile 0 (4 vm-ops/wave)
  for (int kt = 0; kt < ktiles; ++kt) {
    unsigned short* Ac = (kt & 1) ? A1 : A0;
    unsigned short* Bc = (kt & 1) ? B1 : B0;
    unsigned short* An = (kt & 1) ? A0 : A1;
    unsigned short* Bn = (kt & 1) ? B0 : B1;
    if (kt + 1 < ktiles) {
      stage_tile64(Ag, Bg, (kt + 1) * 64, An, Bn, tid);   // +4 vm-ops, in flight
      __builtin_amdgcn_sched_barrier(0);
      asm volatile("s_waitcnt vmcnt(4)" ::: "memory");    // tile kt (own share) landed
    } else {
      __builtin_amdgcn_sched_barrier(0);
      asm volatile("s_waitcnt vmcnt(0)" ::: "memory");    // last tile: full drain
    }
    __builtin_amdgcn_s_barrier();             // all waves' shares of kt landed
    __builtin_amdgcn_sched_barrier(0);        // no ds_read hoists above this
    mfma_tile64(Ac, Bc, arow, brow, quad, xk, acc);
    __builtin_amdgcn_sched_barrier(0);
    asm volatile("s_waitcnt lgkmcnt(0)" ::: "memory");    // (already 0 via MFMA deps)
    __builtin_amdgcn_s_barrier();             // kt's buffers reusable next iter
    __builtin_amdgcn_sched_barrier(0);
  }
}

// bijective XCD swizzle for 1024 blocks (mixer mapping, r11-proven)
__device__ __forceinline__ int xcd_swizzle_1024(int bid) {
  return ((bid & 7) << 7) | (bid >> 3);
}

// ---------------- mixer GEMM: Z = tril(M)@Xn + tri_b + inputs ----------------
__global__ __launch_bounds__(512, 4) void gemm_mixer(
    const unsigned short* __restrict__ Mb, const unsigned short* __restrict__ XnT,
    const float* __restrict__ trib, const float* __restrict__ inp,
    unsigned short* __restrict__ Z, float* __restrict__ red2) {
  __shared__ __align__(16) unsigned short lds[32768];   // 64 KB
  const int swz = xcd_swizzle_1024((int)blockIdx.x);
  const int b = swz >> 4;
  const int i0 = ((swz >> 2) & 3) * 128;
  const int c0 = (swz & 3) * 128;
  f32x4 acc[4][2];
#pragma unroll
  for (int m = 0; m < 4; ++m)
#pragma unroll
    for (int n = 0; n < 2; ++n) acc[m][n] = (f32x4){0.f, 0.f, 0.f, 0.f};
  // tril: rows < i0+128 only need k < i0+128 -> ktiles = (i0+128)/64
  gemm_mainloop64(Mb + (size_t)i0 * T_, XnT + (size_t)b * TC_ + (size_t)c0 * T_,
                  (i0 >> 6) + 2, lds, acc, (int)threadIdx.x);
  const int tid = threadIdx.x, lane = tid & 63, w = tid >> 6;
  const int wm = w >> 2, wn = w & 3, m16 = lane & 15, quad = lane >> 4;
  const int rbase = i0 + wm * 64, cbase = c0 + wn * 32;
  float s1 = 0.f, s2 = 0.f;
#pragma unroll
  for (int m = 0; m < 4; ++m) {
#pragma unroll
    for (int g = 0; g < 4; ++g) {
      const int i = rbase + m * 16 + quad * 4 + g;
      const float tb = trib[i];
      const float* inrow = &inp[((size_t)b * T_ + i) * C_];
      unsigned short* zrow = &Z[((size_t)b * T_ + i) * C_];
#pragma unroll
      for (int n = 0; n < 2; ++n) {
        const int ch = cbase + n * 16 + m16;
        const float v = acc[m][n][g] + tb + inrow[ch];
        zrow[ch] = f2bf(v);
        s1 += v; s2 += v * v;
      }
    }
  }
#pragma unroll
  for (int o = 32; o; o >>= 1) { s1 += __shfl_down(s1, o, 64); s2 += __shfl_down(s2, o, 64); }
  __shared__ float smf[16];
  if (lane == 0) { smf[w * 2] = s1; smf[w * 2 + 1] = s2; }
  __syncthreads();
  if (tid == 0) {
    float a = 0.f, c2 = 0.f;
    for (int i = 0; i < 8; ++i) { a += smf[2 * i]; c2 += smf[2 * i + 1]; }
    atomicAdd(&red2[b * 2], a);
    atomicAdd(&red2[b * 2 + 1], c2);
  }
}

// ---------------- ln2 normalize, IN-PLACE (X2 == Z) ----------------
__global__ __launch_bounds__(256) void ln2_norm(
    unsigned short* Z, const float* __restrict__ red2,
    const float* __restrict__ w, const float* __restrict__ bvec) {
  const size_t e = ((size_t)blockIdx.x * 256 + threadIdx.x) * 8;
  const int b = (int)(e >> 18);
  const int tc = (int)(e & (TC_ - 1));
  const float mu = red2[b * 2] * (1.f / TC_);
  const float rstd = rsqrtf(red2[b * 2 + 1] * (1.f / TC_) - mu * mu + 1e-5f);
  uint4 zp = *(const uint4*)&Z[e];
  const unsigned short* zs = (const unsigned short*)&zp;
  alignas(16) float wv[8], bb[8];
  *(float4*)&wv[0] = *(const float4*)&w[tc];
  *(float4*)&wv[4] = *(const float4*)&w[tc + 4];
  *(float4*)&bb[0] = *(const float4*)&bvec[tc];
  *(float4*)&bb[4] = *(const float4*)&bvec[tc + 4];
  alignas(16) unsigned short o[8];
#pragma unroll
  for (int j = 0; j < 8; ++j)
    o[j] = f2bf((bf2f(zs[j]) - mu) * rstd * wv[j] + bb[j]);
  *(uint4*)&Z[e] = *(const uint4*)&o[0];
}

// d1/d2 tile mapping: each XCD owns 32 consecutive i-tiles x all 4 n-tiles
// -> per-XCD X2/H working set = 32*128 rows * 512 * 2B = 4 MB = fits L2.
__device__ __forceinline__ void mlp_tile_map(int bid, int* i0, int* n0) {
  const int xcd = bid & 7;
  const int idx = bid >> 3;                 // 0..127 within XCD
  *i0 = (xcd * 32 + (idx & 31)) * 128;
  *n0 = (idx >> 5) * 128;
}

// ---------------- MLP GEMM 1: H = gelu(X2 @ W1^T + b1) ----------------
__global__ __launch_bounds__(512, 4) void gemm_d1(
    const unsigned short* __restrict__ X2, const unsigned short* __restrict__ W1b,
    const float* __restrict__ d1b, unsigned short* __restrict__ H) {
  __shared__ __align__(16) unsigned short lds[32768];
  int i0, n0;
  mlp_tile_map((int)blockIdx.x, &i0, &n0);
  f32x4 acc[4][2];
#pragma unroll
  for (int m = 0; m < 4; ++m)
#pragma unroll
    for (int n = 0; n < 2; ++n) acc[m][n] = (f32x4){0.f, 0.f, 0.f, 0.f};
  gemm_mainloop64(X2 + (size_t)i0 * C_, W1b + (size_t)n0 * C_, 8, lds, acc,
                  (int)threadIdx.x);
  const int tid = threadIdx.x, lane = tid & 63, w = tid >> 6;
  const int wm = w >> 2, wn = w & 3, m16 = lane & 15, quad = lane >> 4;
  const int rbase = i0 + wm * 64, cbase = n0 + wn * 32;
#pragma unroll
  for (int m = 0; m < 4; ++m) {
#pragma unroll
    for (int g = 0; g < 4; ++g) {
      const int row = rbase + m * 16 + quad * 4 + g;
#pragma unroll
      for (int n = 0; n < 2; ++n) {
        const int col = cbase + n * 16 + m16;
        const float v = acc[m][n][g] + d1b[col];
        const float gl = 0.5f * v * (1.0f + erff(v * 0.70710678118654752f));
        H[(size_t)row * C_ + col] = f2bf(gl);
      }
    }
  }
}

// ---------------- MLP GEMM 2: out = X2 + H @ W2^T + b2 ----------------
__global__ __launch_bounds__(512, 4) void gemm_d2(
    const unsigned short* __restrict__ H, const unsigned short* __restrict__ W2b,
    const float* __restrict__ d2b, const unsigned short* __restrict__ X2,
    float* __restrict__ out) {
  __shared__ __align__(16) unsigned short lds[32768];
  int i0, n0;
  mlp_tile_map((int)blockIdx.x, &i0, &n0);
  f32x4 acc[4][2];
#pragma unroll
  for (int m = 0; m < 4; ++m)
#pragma unroll
    for (int n = 0; n < 2; ++n) acc[m][n] = (f32x4){0.f, 0.f, 0.f, 0.f};
  gemm_mainloop64(H + (size_t)i0 * C_, W2b + (size_t)n0 * C_, 8, lds, acc,
                  (int)threadIdx.x);
  const int tid = threadIdx.x, lane = tid & 63, w = tid >> 6;
  const int wm = w >> 2, wn = w & 3, m16 = lane & 15, quad = lane >> 4;
  const int rbase = i0 + wm * 64, cbase = n0 + wn * 32;
#pragma unroll
  for (int m = 0; m < 4; ++m) {
#pragma unroll
    for (int g = 0; g < 4; ++g) {
      const int row = rbase + m * 16 + quad * 4 + g;
#pragma unroll
      for (int n = 0; n < 2; ++n) {
        const int col = cbase + n * 16 + m16;
        out[(size_t)row * C_ + col] =
            acc[m][n][g] + d2b[col] + bf2f(X2[(size_t)row * C_ + col]);
      }
    }
  }
}

extern "C" void kernel_launch(void* const* d_in, const int* in_sizes, int n_in,
                              void* d_out, int out_size, void* d_ws, size_t ws_size,
                              hipStream_t stream) {
  const float* inp  = (const float*)d_in[0];
  const float* ln1w = (const float*)d_in[1];
  const float* ln1b = (const float*)d_in[2];
  const float* ln2w = (const float*)d_in[3];
  const float* ln2b = (const float*)d_in[4];
  const float* triM = (const float*)d_in[5];
  const float* trib = (const float*)d_in[6];
  const float* d1w  = (const float*)d_in[7];
  const float* d1b  = (const float*)d_in[8];
  const float* d2w  = (const float*)d_in[9];
  const float* d2b  = (const float*)d_in[10];
  float* out = (float*)d_out;

  char* ws = (char*)d_ws;
  float* red1p = (float*)ws;                        // 1024*2 floats (8 KB)
  float* red2  = (float*)(ws + 8192);               // 64*2 floats
  unsigned short* Mb  = (unsigned short*)(ws + 16384);
  unsigned short* W1b = Mb + TC_;
  unsigned short* W2b = W1b + TC_;
  unsigned short* XnT = W2b + TC_;                  // [B][C][T] bf16; H aliases
  unsigned short* Z   = XnT + (size_t)B_ * TC_;     // [B][T][C] bf16; X2 in-place
  unsigned short* H   = XnT;                        // alias: XnT dead after mixer
  unsigned short* X2  = Z;                          // alias: ln2 is in-place

  prep<<<2048, 256, 0, stream>>>(triM, d1w, d2w, Mb, W1b, W2b, inp, red1p, red2);
  ln1_norm_t<<<dim3(8, 8, B_), 256, 0, stream>>>(inp, ln1w, ln1b, red1p, XnT);
  gemm_mixer<<<1024, 512, 0, stream>>>(Mb, XnT, trib, inp, Z, red2);
  ln2_norm<<<8192, 256, 0, stream>>>(Z, red2, ln2w, ln2b);
  gemm_d1<<<1024, 512, 0, stream>>>(X2, W1b, d1b, H);
  gemm_d2<<<1024, 512, 0, stream>>>(H, W2b, d2b, X2, out);
}

// Round 15
// 255.379 us; speedup vs baseline: 1.6018x; 1.0112x over previous
//
#include <hip/hip_runtime.h>
#include <hip/hip_bf16.h>
#include <math.h>

// Mixer2dTriU: B=64, T=512, C=512, fp32 in/out.
// 6 dispatches (r14 structure, passed):
//   prep / ln1_norm_t / gemm_mixer / ln2_norm(in-place) / gemm_d1 / gemm_d2
//
// r15 delta: GEMM mainloop -> DEPTH-3 PREFETCH RING.  BK=32, 4 tile-buffers
// (4 x 16 KB = 64 KB, run-proven static size).  Per iter each lane issues 2
// global_load_lds (tile kt+3), then waits s_waitcnt vmcnt(6) -- 3 tiles stay
// in flight across barriers, never draining to 0 mid-loop (catalog T4,
// m218: counted-depth vs drain-0 = +38-73%).  r14's depth-1 variant left
// ~900cyc HBM latency exposed each iter (GEMMs stuck at 3.3 TB/s while the
// harness's own fill kernel streams 6.45 TB/s at 8.5%% occupancy).
// Ring hazard audit: buffer kt&3 re-staged at iter kt+1 AFTER the post-MFMA
// barrier of iter kt (readers done); consumed at iter kt+4 gated by vmcnt.
// Geometry/swizzle = r7/r11-proven BK=32 (key (row>>1)&3, 0 conflicts).
// Spill canary: d1 WRITE_SIZE must stay 32768 KB.  Fallback: r11 verbatim.

#define B_ 64
#define T_ 512
#define C_ 512
#define TC_ (T_ * C_)
static_assert(TC_ == 262144, "");

typedef __attribute__((ext_vector_type(8))) short bf16x8;
typedef __attribute__((ext_vector_type(4))) float f32x4;

__device__ __forceinline__ unsigned short f2bf(float f) {
  union { float f; unsigned u; } v; v.f = f;
  unsigned r = v.u + 0x7FFF + ((v.u >> 16) & 1);   // RNE
  return (unsigned short)(r >> 16);
}
__device__ __forceinline__ float bf2f(unsigned short h) {
  union { unsigned u; float f; } v; v.u = ((unsigned)h) << 16; return v.f;
}

// async global -> LDS, 16 B per lane (global_load_lds_dwordx4)
__device__ __forceinline__ void load16_lds(const void* gsrc, void* ldst) {
  __builtin_amdgcn_global_load_lds(
      (const __attribute__((address_space(1))) unsigned int*)gsrc,
      (__attribute__((address_space(3))) unsigned int*)ldst,
      16, 0, 0);
}

// ------------- prep: weights->bf16 + ln1 partial stats + zero red2 -------------
__global__ __launch_bounds__(256) void prep(
    const float* __restrict__ triM, const float* __restrict__ d1w,
    const float* __restrict__ d2w, unsigned short* __restrict__ Mb,
    unsigned short* __restrict__ W1b, unsigned short* __restrict__ W2b,
    const float* __restrict__ x, float* __restrict__ red1p,
    float* __restrict__ red2) {
  if (blockIdx.x < 1024) {
    if (blockIdx.x == 0 && threadIdx.x < 128) red2[threadIdx.x] = 0.f;
    const int idx = blockIdx.x * 256 + threadIdx.x;   // 262144 total
    const int i = idx >> 9, j = idx & 511;
    Mb[idx]  = (j <= i) ? f2bf(triM[idx]) : (unsigned short)0;
    W1b[idx] = f2bf(d1w[idx]);
    W2b[idx] = f2bf(d2w[idx]);
    return;
  }
  // ln1 stats: per-(batch,split) partials, NO atomics, NO memset dependency
  const int bb = blockIdx.x - 1024;               // = b*16 + s
  const int b = bb >> 4, s = bb & 15;
  const float4* p = (const float4*)(x + (size_t)b * TC_) + (size_t)s * 4096;
  float s1 = 0.f, s2 = 0.f;
  for (int i = threadIdx.x; i < 4096; i += 256) {
    float4 v = p[i];
    s1 += v.x + v.y + v.z + v.w;
    s2 += v.x * v.x + v.y * v.y + v.z * v.z + v.w * v.w;
  }
#pragma unroll
  for (int o = 32; o; o >>= 1) { s1 += __shfl_down(s1, o, 64); s2 += __shfl_down(s2, o, 64); }
  __shared__ float sm[8];
  const int w = threadIdx.x >> 6, lane = threadIdx.x & 63;
  if (lane == 0) { sm[w * 2] = s1; sm[w * 2 + 1] = s2; }
  __syncthreads();
  if (threadIdx.x == 0) {
    float a = 0.f, c = 0.f;
    for (int i = 0; i < 4; ++i) { a += sm[2 * i]; c += sm[2 * i + 1]; }
    red1p[bb * 2] = a;
    red1p[bb * 2 + 1] = c;
  }
}

// ------------- ln1 normalize + transposed bf16 write -------------
__global__ __launch_bounds__(256) void ln1_norm_t(
    const float* __restrict__ x, const float* __restrict__ w,
    const float* __restrict__ bvec, const float* __restrict__ red1p,
    unsigned short* __restrict__ XnT) {
  __shared__ unsigned short tile[64][65];
  const int b = blockIdx.z;
  const int t0 = blockIdx.y * 64;
  const int c0 = blockIdx.x * 64;
  float s1 = 0.f, s2 = 0.f;
#pragma unroll
  for (int i = 0; i < 16; ++i) {
    s1 += red1p[(b * 16 + i) * 2];
    s2 += red1p[(b * 16 + i) * 2 + 1];
  }
  const float mu = s1 * (1.f / TC_);
  const float rstd = rsqrtf(s2 * (1.f / TC_) - mu * mu + 1e-5f);
  const int tid = threadIdx.x;
  const int r = tid >> 4;            // 0..15
  const int cg = (tid & 15) * 4;     // 0..60
#pragma unroll
  for (int rr = 0; rr < 4; ++rr) {
    const int t = t0 + rr * 16 + r;
    const float4 xv = *(const float4*)&x[((size_t)b * T_ + t) * C_ + c0 + cg];
    const float4 wv = *(const float4*)&w[(size_t)t * C_ + c0 + cg];
    const float4 bv = *(const float4*)&bvec[(size_t)t * C_ + c0 + cg];
    tile[rr * 16 + r][cg + 0] = f2bf((xv.x - mu) * rstd * wv.x + bv.x);
    tile[rr * 16 + r][cg + 1] = f2bf((xv.y - mu) * rstd * wv.y + bv.y);
    tile[rr * 16 + r][cg + 2] = f2bf((xv.z - mu) * rstd * wv.z + bv.z);
    tile[rr * 16 + r][cg + 3] = f2bf((xv.w - mu) * rstd * wv.w + bv.w);
  }
  __syncthreads();
  const int cl = tid >> 2;           // 0..63
  const int tg = (tid & 3) * 16;     // 0,16,32,48
  alignas(16) unsigned short tmp[16];
#pragma unroll
  for (int j = 0; j < 16; ++j) tmp[j] = tile[tg + j][cl];
  unsigned short* o = &XnT[((size_t)b * C_ + c0 + cl) * T_ + t0 + tg];
  *(uint4*)&o[0] = *(const uint4*)&tmp[0];
  *(uint4*)&o[8] = *(const uint4*)&tmp[8];
}

// ===== 128x128 GEMM, BK=32, 8 waves, 4-buffer ring, depth-3 prefetch =====
// A rows = C rows (at i0), B rows = C cols (at n0); both ld = 512 shorts.
// LDS: 4 buffers x (A[128][32] + B[128][32]) = 4 x 16 KB = 64 KB.
// Tile chunk swizzle: phys 16B-chunk p of row holds logical p ^ ((row>>1)&3)
// (r1/r7-measured 0 conflicts).  2 vm-ops per lane per stage.
__device__ __forceinline__ void stage32(
    const unsigned short* __restrict__ Ag, const unsigned short* __restrict__ Bg,
    int k0, unsigned short* As, unsigned short* Bs, int tid) {
  const int row = tid >> 2;
  const int l = ((tid & 3) ^ ((row >> 1) & 3)) * 8;    // swizzled k-off (shorts)
  load16_lds(Ag + ((size_t)row << 9) + k0 + l, As + tid * 8);
  load16_lds(Bg + ((size_t)row << 9) + k0 + l, Bs + tid * 8);
}

__device__ __forceinline__ void mfma32(
    const unsigned short* __restrict__ As, const unsigned short* __restrict__ Bs,
    int arow, int brow, int co, f32x4 acc[4][2]) {
  bf16x8 af[4], bfr[2];
#pragma unroll
  for (int m = 0; m < 4; ++m)
    af[m] = *(const bf16x8*)&As[arow + m * 512 + co];
#pragma unroll
  for (int n = 0; n < 2; ++n)
    bfr[n] = *(const bf16x8*)&Bs[brow + n * 512 + co];
  __builtin_amdgcn_s_setprio(1);
#pragma unroll
  for (int m = 0; m < 4; ++m)
#pragma unroll
    for (int n = 0; n < 2; ++n)
      acc[m][n] = __builtin_amdgcn_mfma_f32_16x16x32_bf16(af[m], bfr[n], acc[m][n], 0, 0, 0);
  __builtin_amdgcn_s_setprio(0);
}

__device__ __forceinline__ void gemm_ring32(
    const unsigned short* __restrict__ Ag, const unsigned short* __restrict__ Bg,
    int ktiles,                               // >= 4 here (4,8,12,16)
    unsigned short* lds, f32x4 acc[4][2], int tid) {
  const int lane = tid & 63;
  const int w = tid >> 6;
  const int wm = w >> 2, wn = w & 3;          // 2 x 4 wave grid
  const int m16 = lane & 15, quad = lane >> 4;
  const int arow = (wm * 64 + m16) * 32;      // shorts (row stride 32)
  const int brow = (wn * 32 + m16) * 32;
  const int co = (quad ^ ((m16 >> 1) & 3)) * 8;
  // prologue: stage tiles 0,1,2 (6 vm-ops/lane outstanding)
#pragma unroll
  for (int t = 0; t < 3; ++t)
    stage32(Ag, Bg, t * 32, lds + t * 8192, lds + t * 8192 + 4096, tid);
  for (int kt = 0; kt < ktiles; ++kt) {
    const int nxt = kt + 3;
    if (nxt < ktiles)                         // stage tile kt+3 into ring slot
      stage32(Ag, Bg, nxt * 32, lds + (nxt & 3) * 8192,
              lds + (nxt & 3) * 8192 + 4096, tid);
    const int ahead = ktiles - 1 - kt;        // tiles still in flight after kt
    __builtin_amdgcn_sched_barrier(0);
    if (ahead >= 3)      asm volatile("s_waitcnt vmcnt(6)" ::: "memory");
    else if (ahead == 2) asm volatile("s_waitcnt vmcnt(4)" ::: "memory");
    else if (ahead == 1) asm volatile("s_waitcnt vmcnt(2)" ::: "memory");
    else                 asm volatile("s_waitcnt vmcnt(0)" ::: "memory");
    __builtin_amdgcn_s_barrier();             // all waves' shares of kt landed
    __builtin_amdgcn_sched_barrier(0);
    mfma32(lds + (kt & 3) * 8192, lds + (kt & 3) * 8192 + 4096,
           arow, brow, co, acc);
    __builtin_amdgcn_sched_barrier(0);
    asm volatile("s_waitcnt lgkmcnt(0)" ::: "memory");    // ds_reads complete
    __builtin_amdgcn_s_barrier();             // slot kt&3 reusable at iter kt+1
    __builtin_amdgcn_sched_barrier(0);
  }
}

// bijective XCD swizzle for 1024 blocks (mixer mapping, r11-proven)
__device__ __forceinline__ int xcd_swizzle_1024(int bid) {
  return ((bid & 7) << 7) | (bid >> 3);
}

// ---------------- mixer GEMM: Z = tril(M)@Xn + tri_b + inputs ----------------
__global__ __launch_bounds__(512, 4) void gemm_mixer(
    const unsigned short* __restrict__ Mb, const unsigned short* __restrict__ XnT,
    const float* __restrict__ trib, const float* __restrict__ inp,
    unsigned short* __restrict__ Z, float* __restrict__ red2) {
  __shared__ __align__(16) unsigned short lds[32768];   // 64 KB ring
  const int swz = xcd_swizzle_1024((int)blockIdx.x);
  const int b = swz >> 4;
  const int i0 = ((swz >> 2) & 3) * 128;
  const int c0 = (swz & 3) * 128;
  f32x4 acc[4][2];
#pragma unroll
  for (int m = 0; m < 4; ++m)
#pragma unroll
    for (int n = 0; n < 2; ++n) acc[m][n] = (f32x4){0.f, 0.f, 0.f, 0.f};
  // tril: rows < i0+128 only need k < i0+128 -> ktiles = (i0+128)/32
  gemm_ring32(Mb + (size_t)i0 * T_, XnT + (size_t)b * TC_ + (size_t)c0 * T_,
              (i0 >> 5) + 4, lds, acc, (int)threadIdx.x);
  const int tid = threadIdx.x, lane = tid & 63, w = tid >> 6;
  const int wm = w >> 2, wn = w & 3, m16 = lane & 15, quad = lane >> 4;
  const int rbase = i0 + wm * 64, cbase = c0 + wn * 32;
  float s1 = 0.f, s2 = 0.f;
#pragma unroll
  for (int m = 0; m < 4; ++m) {
#pragma unroll
    for (int g = 0; g < 4; ++g) {
      const int i = rbase + m * 16 + quad * 4 + g;
      const float tb = trib[i];
      const float* inrow = &inp[((size_t)b * T_ + i) * C_];
      unsigned short* zrow = &Z[((size_t)b * T_ + i) * C_];
#pragma unroll
      for (int n = 0; n < 2; ++n) {
        const int ch = cbase + n * 16 + m16;
        const float v = acc[m][n][g] + tb + inrow[ch];
        zrow[ch] = f2bf(v);
        s1 += v; s2 += v * v;
      }
    }
  }
#pragma unroll
  for (int o = 32; o; o >>= 1) { s1 += __shfl_down(s1, o, 64); s2 += __shfl_down(s2, o, 64); }
  __shared__ float smf[16];
  if (lane == 0) { smf[w * 2] = s1; smf[w * 2 + 1] = s2; }
  __syncthreads();
  if (tid == 0) {
    float a = 0.f, c2 = 0.f;
    for (int i = 0; i < 8; ++i) { a += smf[2 * i]; c2 += smf[2 * i + 1]; }
    atomicAdd(&red2[b * 2], a);
    atomicAdd(&red2[b * 2 + 1], c2);
  }
}

// ---------------- ln2 normalize, IN-PLACE (X2 == Z) ----------------
__global__ __launch_bounds__(256) void ln2_norm(
    unsigned short* Z, const float* __restrict__ red2,
    const float* __restrict__ w, const float* __restrict__ bvec) {
  const size_t e = ((size_t)blockIdx.x * 256 + threadIdx.x) * 8;
  const int b = (int)(e >> 18);
  const int tc = (int)(e & (TC_ - 1));
  const float mu = red2[b * 2] * (1.f / TC_);
  const float rstd = rsqrtf(red2[b * 2 + 1] * (1.f / TC_) - mu * mu + 1e-5f);
  uint4 zp = *(const uint4*)&Z[e];
  const unsigned short* zs = (const unsigned short*)&zp;
  alignas(16) float wv[8], bb[8];
  *(float4*)&wv[0] = *(const float4*)&w[tc];
  *(float4*)&wv[4] = *(const float4*)&w[tc + 4];
  *(float4*)&bb[0] = *(const float4*)&bvec[tc];
  *(float4*)&bb[4] = *(const float4*)&bvec[tc + 4];
  alignas(16) unsigned short o[8];
#pragma unroll
  for (int j = 0; j < 8; ++j)
    o[j] = f2bf((bf2f(zs[j]) - mu) * rstd * wv[j] + bb[j]);
  *(uint4*)&Z[e] = *(const uint4*)&o[0];
}

// d1/d2 tile mapping: each XCD owns 32 consecutive i-tiles x all 4 n-tiles
// -> per-XCD X2/H working set = 4 MB = fits L2 (r14: FETCH 84->67 MB).
__device__ __forceinline__ void mlp_tile_map(int bid, int* i0, int* n0) {
  const int xcd = bid & 7;
  const int idx = bid >> 3;                 // 0..127 within XCD
  *i0 = (xcd * 32 + (idx & 31)) * 128;
  *n0 = (idx >> 5) * 128;
}

// ---------------- MLP GEMM 1: H = gelu(X2 @ W1^T + b1) ----------------
__global__ __launch_bounds__(512, 4) void gemm_d1(
    const unsigned short* __restrict__ X2, const unsigned short* __restrict__ W1b,
    const float* __restrict__ d1b, unsigned short* __restrict__ H) {
  __shared__ __align__(16) unsigned short lds[32768];
  int i0, n0;
  mlp_tile_map((int)blockIdx.x, &i0, &n0);
  f32x4 acc[4][2];
#pragma unroll
  for (int m = 0; m < 4; ++m)
#pragma unroll
    for (int n = 0; n < 2; ++n) acc[m][n] = (f32x4){0.f, 0.f, 0.f, 0.f};
  gemm_ring32(X2 + (size_t)i0 * C_, W1b + (size_t)n0 * C_, 16, lds, acc,
              (int)threadIdx.x);
  const int tid = threadIdx.x, lane = tid & 63, w = tid >> 6;
  const int wm = w >> 2, wn = w & 3, m16 = lane & 15, quad = lane >> 4;
  const int rbase = i0 + wm * 64, cbase = n0 + wn * 32;
#pragma unroll
  for (int m = 0; m < 4; ++m) {
#pragma unroll
    for (int g = 0; g < 4; ++g) {
      const int row = rbase + m * 16 + quad * 4 + g;
#pragma unroll
      for (int n = 0; n < 2; ++n) {
        const int col = cbase + n * 16 + m16;
        const float v = acc[m][n][g] + d1b[col];
        const float gl = 0.5f * v * (1.0f + erff(v * 0.70710678118654752f));
        H[(size_t)row * C_ + col] = f2bf(gl);
      }
    }
  }
}

// ---------------- MLP GEMM 2: out = X2 + H @ W2^T + b2 ----------------
__global__ __launch_bounds__(512, 4) void gemm_d2(
    const unsigned short* __restrict__ H, const unsigned short* __restrict__ W2b,
    const float* __restrict__ d2b, const unsigned short* __restrict__ X2,
    float* __restrict__ out) {
  __shared__ __align__(16) unsigned short lds[32768];
  int i0, n0;
  mlp_tile_map((int)blockIdx.x, &i0, &n0);
  f32x4 acc[4][2];
#pragma unroll
  for (int m = 0; m < 4; ++m)
#pragma unroll
    for (int n = 0; n < 2; ++n) acc[m][n] = (f32x4){0.f, 0.f, 0.f, 0.f};
  gemm_ring32(H + (size_t)i0 * C_, W2b + (size_t)n0 * C_, 16, lds, acc,
              (int)threadIdx.x);
  const int tid = threadIdx.x, lane = tid & 63, w = tid >> 6;
  const int wm = w >> 2, wn = w & 3, m16 = lane & 15, quad = lane >> 4;
  const int rbase = i0 + wm * 64, cbase = n0 + wn * 32;
#pragma unroll
  for (int m = 0; m < 4; ++m) {
#pragma unroll
    for (int g = 0; g < 4; ++g) {
      const int row = rbase + m * 16 + quad * 4 + g;
#pragma unroll
      for (int n = 0; n < 2; ++n) {
        const int col = cbase + n * 16 + m16;
        out[(size_t)row * C_ + col] =
            acc[m][n][g] + d2b[col] + bf2f(X2[(size_t)row * C_ + col]);
      }
    }
  }
}

extern "C" void kernel_launch(void* const* d_in, const int* in_sizes, int n_in,
                              void* d_out, int out_size, void* d_ws, size_t ws_size,
                              hipStream_t stream) {
  const float* inp  = (const float*)d_in[0];
  const float* ln1w = (const float*)d_in[1];
  const float* ln1b = (const float*)d_in[2];
  const float* ln2w = (const float*)d_in[3];
  const float* ln2b = (const float*)d_in[4];
  const float* triM = (const float*)d_in[5];
  const float* trib = (const float*)d_in[6];
  const float* d1w  = (const float*)d_in[7];
  const float* d1b  = (const float*)d_in[8];
  const float* d2w  = (const float*)d_in[9];
  const float* d2b  = (const float*)d_in[10];
  float* out = (float*)d_out;

  char* ws = (char*)d_ws;
  float* red1p = (float*)ws;                        // 1024*2 floats (8 KB)
  float* red2  = (float*)(ws + 8192);               // 64*2 floats
  unsigned short* Mb  = (unsigned short*)(ws + 16384);
  unsigned short* W1b = Mb + TC_;
  unsigned short* W2b = W1b + TC_;
  unsigned short* XnT = W2b + TC_;                  // [B][C][T] bf16; H aliases
  unsigned short* Z   = XnT + (size_t)B_ * TC_;     // [B][T][C] bf16; X2 in-place
  unsigned short* H   = XnT;                        // alias: XnT dead after mixer
  unsigned short* X2  = Z;                          // alias: ln2 is in-place

  prep<<<2048, 256, 0, stream>>>(triM, d1w, d2w, Mb, W1b, W2b, inp, red1p, red2);
  ln1_norm_t<<<dim3(8, 8, B_), 256, 0, stream>>>(inp, ln1w, ln1b, red1p, XnT);
  gemm_mixer<<<1024, 512, 0, stream>>>(Mb, XnT, trib, inp, Z, red2);
  ln2_norm<<<8192, 256, 0, stream>>>(Z, red2, ln2w, ln2b);
  gemm_d1<<<1024, 512, 0, stream>>>(X2, W1b, d1b, H);
  gemm_d2<<<1024, 512, 0, stream>>>(H, W2b, d2b, X2, out);
}